// Round 3
// baseline (2857.012 us; speedup 1.0000x reference)
//
#include <hip/hip_runtime.h>
#include <hip/hip_bf16.h>

#define T_ 512
#define B_ 64
#define OBS_ 512
#define H_ 1024
#define A_ 18
#define MM_ (T_*B_)   // 32768
#define G4_ (4*H_)    // 4096
#define CH_ 64        // time steps per chunk
#define NCH_ (T_/CH_) // 8 chunks
#define CM_ (CH_*B_)  // 4096 rows per chunk
#define NG_ 256       // fused GEMM worker blocks

typedef unsigned short u16;
typedef unsigned long long u64;
typedef __attribute__((ext_vector_type(8))) short s8v;
typedef __attribute__((ext_vector_type(4))) float f4v;

__device__ __forceinline__ float b2f(u16 u){
    unsigned x = ((unsigned)u) << 16;
    return __builtin_bit_cast(float, x);
}
__device__ __forceinline__ u16 f2b(float f){
    unsigned x = __builtin_bit_cast(unsigned, f);
    return (u16)((x + 0x7fffu + ((x >> 16) & 1u)) >> 16);  // RNE
}

// ---------------- small utility kernels ----------------

__global__ void cast_f32_bf16(const float* __restrict__ in, u16* __restrict__ out, int n){
    int i = blockIdx.x * blockDim.x + threadIdx.x;
    int stride = gridDim.x * blockDim.x;
    for (; i < n; i += stride) out[i] = f2b(in[i]);
}

__global__ void add_bias2(const float* __restrict__ a, const float* __restrict__ b,
                          float* __restrict__ out, int n){
    int i = blockIdx.x * blockDim.x + threadIdx.x;
    if (i < n) out[i] = a[i] + b[i];
}

// zero h_hist[0] (buffer 0), c, and the 512 step-flags ([4 groups][4 quarters][32])
__global__ void init_scan(u16* __restrict__ h_hist, float* __restrict__ c,
                          unsigned* __restrict__ flags){
    int i = blockIdx.x * blockDim.x + threadIdx.x;
    int stride = gridDim.x * blockDim.x;
    unsigned* h0 = (unsigned*)h_hist;
    for (int k = i; k < B_*H_/2; k += stride) h0[k] = 0u;
    for (int k = i; k < B_*H_; k += stride) c[k] = 0.f;
    if (i < 512) flags[i] = 0u;
}

__global__ void copy_hc(const float* __restrict__ h, const float* __restrict__ c,
                        float* __restrict__ out){
    int i = blockIdx.x * blockDim.x + threadIdx.x;  // 65536 threads
    out[(size_t)MM_*A_ + i] = h[i];
    out[(size_t)MM_*A_ + B_*H_ + i] = c[i];
}

// ---------------- bf16 MFMA GEMM: C = act(A @ W^T + bias), W is (N,K) ----------------

#define LDSS 72  // 64 + 8 pad

template<bool A_FP32, bool RELU>
__global__ __launch_bounds__(256) void gemm_bt(
    const void* __restrict__ Aptr, const u16* __restrict__ W,
    const float* __restrict__ bias, u16* __restrict__ C,
    int M, int N, int K)
{
    __shared__ __align__(16) u16 As[128 * LDSS];
    __shared__ __align__(16) u16 Bs[128 * LDSS];

    const int tid  = threadIdx.x;
    const int lane = tid & 63;
    const int wid  = tid >> 6;
    const int wm   = wid & 1, wn = wid >> 1;
    const int m0   = blockIdx.y * 128, n0 = blockIdx.x * 128;
    const int quad = lane >> 4, l16 = lane & 15;

    f4v acc[4][4];
    #pragma unroll
    for (int i = 0; i < 4; i++)
        #pragma unroll
        for (int j = 0; j < 4; j++) acc[i][j] = (f4v){0.f,0.f,0.f,0.f};

    for (int k0 = 0; k0 < K; k0 += 64){
        __syncthreads();
        if (A_FP32){
            const float* A = (const float*)Aptr;
            #pragma unroll
            for (int pss = 0; pss < 8; pss++){
                int idx = pss * 256 + tid;
                int row = idx >> 4, ch = idx & 15;
                float4 v = *(const float4*)(A + (size_t)(m0 + row) * K + k0 + ch * 4);
                u16* d = &As[row * LDSS + ch * 4];
                d[0] = f2b(v.x); d[1] = f2b(v.y); d[2] = f2b(v.z); d[3] = f2b(v.w);
            }
        } else {
            const u16* A = (const u16*)Aptr;
            #pragma unroll
            for (int pss = 0; pss < 4; pss++){
                int idx = pss * 256 + tid;
                int row = idx >> 3, ch = idx & 7;
                *(uint4*)&As[row * LDSS + ch * 8] =
                    *(const uint4*)(A + (size_t)(m0 + row) * K + k0 + ch * 8);
            }
        }
        #pragma unroll
        for (int pss = 0; pss < 4; pss++){
            int idx = pss * 256 + tid;
            int row = idx >> 3, ch = idx & 7;
            *(uint4*)&Bs[row * LDSS + ch * 8] =
                *(const uint4*)(W + (size_t)(n0 + row) * K + k0 + ch * 8);
        }
        __syncthreads();

        #pragma unroll
        for (int kk = 0; kk < 64; kk += 32){
            s8v af[4], bf[4];
            #pragma unroll
            for (int mt = 0; mt < 4; mt++)
                af[mt] = *(const s8v*)&As[(wm*64 + mt*16 + l16) * LDSS + kk + quad*8];
            #pragma unroll
            for (int nt = 0; nt < 4; nt++)
                bf[nt] = *(const s8v*)&Bs[(wn*64 + nt*16 + l16) * LDSS + kk + quad*8];
            #pragma unroll
            for (int mt = 0; mt < 4; mt++)
                #pragma unroll
                for (int nt = 0; nt < 4; nt++)
                    acc[mt][nt] = __builtin_amdgcn_mfma_f32_16x16x32_bf16(
                        af[mt], bf[nt], acc[mt][nt], 0, 0, 0);
        }
    }

    #pragma unroll
    for (int mt = 0; mt < 4; mt++){
        #pragma unroll
        for (int nt = 0; nt < 4; nt++){
            #pragma unroll
            for (int r = 0; r < 4; r++){
                int m = m0 + wm*64 + mt*16 + quad*4 + r;
                int n = n0 + wn*64 + nt*16 + l16;
                float v = acc[mt][nt][r] + bias[n];
                if (RELU) v = fmaxf(v, 0.f);
                C[(size_t)m * N + n] = f2b(v);
            }
        }
    }
}

// ---------------- fused: LSTM scan (blocks 0..255, s_setprio(1)) +
//                  workers (blocks 256+): next-chunk xg GEMM, then decode(c-1) --
// Scan protocol is IDENTICAL to the validated per-(group,quarter) flag rendezvous.
// NEW vs R2:
//  (1) scan waves run at s_setprio(1); worker waves stay 0. The scan wave is
//      memory-stalled most of the step (workers fill those slots), but when it
//      IS issue-ready it wins SIMD arbitration -- protecting the latency-critical
//      chain from the co-resident worker's MFMA/LDS instruction stream.
//  (2) workers, after their xg tiles, decode the PREVIOUS chunk (h_hist double-
//      buffered so scan(c) writes buffer c&1 while decode reads (c-1)&1).
//      Removes 7 standalone decode dispatches from the serial timeline.
// Workers touch no flags; correctness never depends on their placement/timing.

__global__ __launch_bounds__(256, 1) void fused_scan_gemm(
    const u16* __restrict__ xg,      // [CH_][64][4096] chunk c (consumed by scan)
    const u16* __restrict__ Whh,     // [4096][1024]
    u16* __restrict__ h_hist,        // [CH_+1][64][1024] current buffer; [0] = incoming h
    u16* __restrict__ h_next,        // next chunk's buffer (seed target for h_hist[0])
    float* __restrict__ c_glob,      // [64][1024] fp32, persists across chunks
    float* __restrict__ h_f32,       // final-h staging (t == T-1 only)
    const float* __restrict__ mask,  // chunk-local
    unsigned* __restrict__ flags,    // [4][4][32] monotonic step flags (128B/line)
    int t0,
    const u16* __restrict__ encA,    // enc rows of chunk c+1 (worker input)
    const u16* __restrict__ Wih,     // [4096][1024]
    const float* __restrict__ bias2, // bih + bhh
    u16* __restrict__ xg_next,       // xg buffer for chunk c+1 (worker output)
    int ntiles,                      // 1024, or 0 on the last chunk
    const u16* __restrict__ Wdec,    // [18][1024] bf16
    const float* __restrict__ bdec,  // [18]
    const u16* __restrict__ dec_latent, // h_prev buffer + B_*H_ (steps 1..CH_), or null
    const float* __restrict__ dec_mask, // mask rows of chunk c-1
    float* __restrict__ dec_out)        // out rows of chunk c-1
{
    __shared__ __align__(16) char smem[2 * 128 * LDSS * 2];  // 36864 B, unioned

    const int tid  = threadIdx.x;
    const int lane = tid & 63;
    const int w    = tid >> 6;
    const int quad = lane >> 4, l16 = lane & 15;

    if (blockIdx.x >= 256){
        // ================= worker path =================
        if (ntiles > 0){
            u16* As = (u16*)smem;
            u16* Bs = As + 128 * LDSS;
            const int wm = w & 1, wn = w >> 1;

            for (int tile = (int)blockIdx.x - 256; tile < ntiles; tile += NG_){
                const int n0 = (tile & 31) * 128;
                const int m0 = (tile >> 5) * 128;

                f4v acc[4][4];
                #pragma unroll
                for (int i = 0; i < 4; i++)
                    #pragma unroll
                    for (int j = 0; j < 4; j++) acc[i][j] = (f4v){0.f,0.f,0.f,0.f};

                for (int k0 = 0; k0 < H_; k0 += 64){
                    __syncthreads();
                    #pragma unroll
                    for (int pss = 0; pss < 4; pss++){
                        int idx = pss * 256 + tid;
                        int row = idx >> 3, ch = idx & 7;
                        *(uint4*)&As[row * LDSS + ch * 8] =
                            *(const uint4*)(encA + (size_t)(m0 + row) * H_ + k0 + ch * 8);
                        *(uint4*)&Bs[row * LDSS + ch * 8] =
                            *(const uint4*)(Wih + (size_t)(n0 + row) * H_ + k0 + ch * 8);
                    }
                    __syncthreads();

                    #pragma unroll
                    for (int kk = 0; kk < 64; kk += 32){
                        s8v af[4], bf[4];
                        #pragma unroll
                        for (int mt = 0; mt < 4; mt++)
                            af[mt] = *(const s8v*)&As[(wm*64 + mt*16 + l16) * LDSS + kk + quad*8];
                        #pragma unroll
                        for (int nt = 0; nt < 4; nt++)
                            bf[nt] = *(const s8v*)&Bs[(wn*64 + nt*16 + l16) * LDSS + kk + quad*8];
                        #pragma unroll
                        for (int mt = 0; mt < 4; mt++)
                            #pragma unroll
                            for (int nt = 0; nt < 4; nt++)
                                acc[mt][nt] = __builtin_amdgcn_mfma_f32_16x16x32_bf16(
                                    af[mt], bf[nt], acc[mt][nt], 0, 0, 0);
                    }
                }
                __syncthreads();  // protect As/Bs before next tile's writes

                #pragma unroll
                for (int mt = 0; mt < 4; mt++){
                    #pragma unroll
                    for (int nt = 0; nt < 4; nt++){
                        #pragma unroll
                        for (int r = 0; r < 4; r++){
                            int m = m0 + wm*64 + mt*16 + quad*4 + r;
                            int n = n0 + wn*64 + nt*16 + l16;
                            xg_next[(size_t)m * G4_ + n] = f2b(acc[mt][nt][r] + bias2[n]);
                        }
                    }
                }
            }
        }

        // ---- decode previous chunk (fabric-light: LLC-resident latent) ----
        if (dec_latent){
            __syncthreads();
            u16* wl = (u16*)smem;  // A_*H_*2 = 36864 B, exact fit
            for (int i = tid; i < A_ * H_ / 8; i += 256)
                ((uint4*)wl)[i] = ((const uint4*)Wdec)[i];
            __syncthreads();

            int wid = ((int)blockIdx.x - 256) * 4 + w;
            for (int row = wid; row < CM_; row += NG_ * 4){
                float lat[16];
                #pragma unroll
                for (int i = 0; i < 16; i++)
                    lat[i] = b2f(dec_latent[(size_t)row * H_ + i*64 + lane]);
                float dacc[A_];
                #pragma unroll
                for (int a = 0; a < A_; a++) dacc[a] = 0.f;
                #pragma unroll
                for (int i = 0; i < 16; i++){
                    #pragma unroll
                    for (int a = 0; a < A_; a++)
                        dacc[a] += lat[i] * b2f(wl[a * H_ + i*64 + lane]);
                }
                float mm = dec_mask[row];
                #pragma unroll
                for (int a = 0; a < A_; a++){
                    float v = dacc[a];
                    #pragma unroll
                    for (int sh = 32; sh > 0; sh >>= 1) v += __shfl_down(v, sh, 64);
                    if (lane == 0) dec_out[(size_t)row * A_ + a] = (v + bdec[a]) * mm;
                }
            }
        }
        return;
    }

    // ================= scan path (unchanged protocol + setprio) =================
    __builtin_amdgcn_s_setprio(1);  // win SIMD arbitration over co-resident worker wave

    float (*red)[4][16][17] = (float(*)[4][16][17])smem;  // [wave][gate][batch][unit+pad]

    const int bid  = blockIdx.x;
    const int g = bid & 3, s = bid >> 2;
    const int rb0 = g * 16, j0 = s * 16;

    // Whh B-fragments: B[n=lane&15][k=quad*8+j] [m89]
    const int koff = w * 256;
    s8v bf[4][8];
    #pragma unroll
    for (int gate = 0; gate < 4; gate++)
        #pragma unroll
        for (int ks = 0; ks < 8; ks++)
            bf[gate][ks] = *(const s8v*)(
                Whh + (size_t)(gate * H_ + j0 + l16) * H_ + koff + ks * 32 + quad * 8);

    const int cb = tid >> 4, cu = tid & 15;
    const size_t cidx = (size_t)(rb0 + cb) * H_ + j0 + cu;
    float c_reg = c_glob[cidx];

    const size_t hoff = (size_t)(rb0 + l16) * H_ + koff + quad * 8;  // u16 elems

    // producer flag slot: [g][s>>4][s&15]; consumer wave w polls [g][w][0..15]
    unsigned* myflag = flags + ((g * 4 + (s >> 4)) << 5) + (s & 15);
    const unsigned* pollp = flags + ((g * 4 + w) << 5) + l16;

    // prefetch xg + mask for st = 0
    const u16* xg0 = xg + (size_t)(rb0 + cb) * G4_ + j0 + cu;
    u16 nxi = xg0[0], nxf = xg0[H_], nxv = xg0[2 * H_], nxo = xg0[3 * H_];
    float nm = mask[rb0 + cb];

    for (int st = 0; st < CH_; st++){
        const float xi = b2f(nxi), xf = b2f(nxf), xv = b2f(nxv), xo = b2f(nxo);
        const float m = nm;

        // ---- per-wave flag poll: the 16 producers of THIS wave's K-quarter
        const unsigned tgt = (unsigned)(t0 + st);
        int tries = 0;
        for (;;){
            unsigned f = __hip_atomic_load(pollp, __ATOMIC_RELAXED, __HIP_MEMORY_SCOPE_AGENT);
            if (__all((int)(f >= tgt))) break;
            if (++tries > (1 << 20)) break;  // backstop: fail visibly, never hang
            if (tries >= 8) __builtin_amdgcn_s_sleep(1);  // thin the poll storm
        }

        // ---- h loads (fresh: first touch after gate) + MFMA
        const u16* hs = h_hist + (size_t)st * B_ * H_ + hoff;
        f4v acc[4];
        #pragma unroll
        for (int gate = 0; gate < 4; gate++) acc[gate] = (f4v){0.f,0.f,0.f,0.f};
        #pragma unroll
        for (int ks = 0; ks < 8; ks++){
            s8v af = *(const s8v*)(hs + ks * 32);
            #pragma unroll
            for (int gate = 0; gate < 4; gate++)
                acc[gate] = __builtin_amdgcn_mfma_f32_16x16x32_bf16(af, bf[gate][ks], acc[gate], 0, 0, 0);
        }
        #pragma unroll
        for (int gate = 0; gate < 4; gate++)
            #pragma unroll
            for (int r = 0; r < 4; r++)
                red[w][gate][quad * 4 + r][l16] = acc[gate][r];
        __syncthreads();

        // ---- cell phase
        float gi = xi, gf = xf, gg = xv, go = xo;
        #pragma unroll
        for (int ww = 0; ww < 4; ww++){
            gi += red[ww][0][cb][cu];
            gf += red[ww][1][cb][cu];
            gg += red[ww][2][cb][cu];
            go += red[ww][3][cb][cu];
        }

        float is = 1.f / (1.f + __expf(-gi));
        float fs = 1.f / (1.f + __expf(-gf));
        float os = 1.f / (1.f + __expf(-go));
        float gt = tanhf(gg);

        float cn = fs * c_reg + is * gt;
        float hn = os * tanhf(cn);
        hn *= m; cn *= m;
        c_reg = cn;
        if (t0 + st == T_ - 1) h_f32[cidx] = hn;

        // ---- publish h(st+1): packed u32 sc1 store to LLC
        unsigned hb = (unsigned)f2b(hn);
        unsigned partner = (unsigned)__shfl_xor((int)hb, 1, 64);
        if ((cu & 1) == 0){
            unsigned packed = hb | (partner << 16);
            unsigned* dst = (unsigned*)(h_hist + (size_t)(st + 1) * B_ * H_ + cidx);
            __hip_atomic_store(dst, packed, __ATOMIC_RELAXED, __HIP_MEMORY_SCOPE_AGENT);
            if (st == CH_ - 1){  // seed NEXT chunk's h_hist[0] (double-buffered)
                unsigned* dst0 = (unsigned*)(h_next + cidx);
                __hip_atomic_store(dst0, packed, __ATOMIC_RELAXED, __HIP_MEMORY_SCOPE_AGENT);
            }
        }
        asm volatile("s_waitcnt vmcnt(0)" ::: "memory");  // this wave's h stores acked
        __syncthreads();                                   // all waves acked (also guards red[])

        // ---- release: single plain flag store (no RMW)
        if (tid == 0)
            __hip_atomic_store(myflag, (unsigned)(t0 + st + 1),
                               __ATOMIC_RELAXED, __HIP_MEMORY_SCOPE_AGENT);

        // ---- prefetch next step's xg/mask (after flag store: outside vmcnt window)
        if (st + 1 < CH_){
            const u16* xgn = xg + (size_t)(st + 1) * B_ * G4_ + (size_t)(rb0 + cb) * G4_ + j0 + cu;
            nxi = xgn[0]; nxf = xgn[H_]; nxv = xgn[2 * H_]; nxo = xgn[3 * H_];
            nm = mask[(size_t)(st + 1) * B_ + rb0 + cb];
        }
    }

    c_glob[cidx] = c_reg;
}

// ---------------- decode (standalone; used for the final chunk + fallback) ------

__global__ __launch_bounds__(256) void decode_kernel(
    const u16* __restrict__ latent, const u16* __restrict__ Wdec,
    const float* __restrict__ bdec, const float* __restrict__ mask,
    float* __restrict__ values, int rows)
{
    __shared__ __align__(16) u16 wl[A_ * H_];
    const int tid = threadIdx.x;
    for (int i = tid; i < A_ * H_ / 8; i += 256)
        ((uint4*)wl)[i] = ((const uint4*)Wdec)[i];
    __syncthreads();

    const int lane = tid & 63;
    int wid = blockIdx.x * 4 + (tid >> 6);
    const int nwaves = gridDim.x * 4;

    for (int row = wid; row < rows; row += nwaves){
        float lat[16];
        #pragma unroll
        for (int i = 0; i < 16; i++)
            lat[i] = b2f(latent[(size_t)row * H_ + i*64 + lane]);
        float acc[A_];
        #pragma unroll
        for (int a = 0; a < A_; a++) acc[a] = 0.f;
        #pragma unroll
        for (int i = 0; i < 16; i++){
            #pragma unroll
            for (int a = 0; a < A_; a++)
                acc[a] += lat[i] * b2f(wl[a * H_ + i*64 + lane]);
        }
        float m = mask[row];
        #pragma unroll
        for (int a = 0; a < A_; a++){
            float v = acc[a];
            #pragma unroll
            for (int s = 32; s > 0; s >>= 1) v += __shfl_down(v, s, 64);
            if (lane == 0) values[(size_t)row * A_ + a] = (v + bdec[a]) * m;
        }
    }
}

// ---------------- launcher ----------------

extern "C" void kernel_launch(void* const* d_in, const int* in_sizes, int n_in,
                              void* d_out, int out_size, void* d_ws, size_t ws_size,
                              hipStream_t stream)
{
    const float* obs  = (const float*)d_in[0];
    const float* mask = (const float*)d_in[1];
    const float* Wenc = (const float*)d_in[2];
    const float* benc = (const float*)d_in[3];
    const float* Wih  = (const float*)d_in[4];
    const float* bih  = (const float*)d_in[5];
    const float* Whh  = (const float*)d_in[6];
    const float* bhh  = (const float*)d_in[7];
    const float* Wdec = (const float*)d_in[8];
    const float* bdec = (const float*)d_in[9];
    float* out = (float*)d_out;

    char* p = (char*)d_ws;
    size_t o = 0;
    auto alloc = [&](size_t bytes){ void* r = p + o; o += (bytes + 255) & ~(size_t)255; return r; };
    // common allocations
    u16*      wenc_b  = (u16*)     alloc((size_t)H_ * OBS_ * 2);
    u16*      wih_b   = (u16*)     alloc((size_t)G4_ * H_ * 2);
    u16*      whh_b   = (u16*)     alloc((size_t)G4_ * H_ * 2);
    u16*      wdec_b  = (u16*)     alloc((size_t)A_ * H_ * 2);
    float*    bias2   = (float*)   alloc((size_t)G4_ * 4);
    u16*      h_buf0  = (u16*)     alloc((size_t)(CH_ + 1) * B_ * H_ * 2);  // 8.3 MB
    float*    h_f32   = (float*)   alloc((size_t)B_ * H_ * 4);
    float*    c_f32   = (float*)   alloc((size_t)B_ * H_ * 4);
    unsigned* flags   = (unsigned*)alloc(512 * 4);   // [4][4][32] u32

    const size_t hbuf_b    = (size_t)(CH_ + 1) * B_ * H_ * 2;
    const size_t enc_all_b = (size_t)MM_ * H_ * 2;   // 67.1 MB
    const size_t xg_b      = (size_t)CM_ * G4_ * 2;  // 33.5 MB each
    const bool big = ws_size >= o + hbuf_b + enc_all_b + 2 * xg_b + 4096;
    (void)in_sizes; (void)n_in; (void)out_size;

    cast_f32_bf16<<<1024, 256, 0, stream>>>(Wenc, wenc_b, H_ * OBS_);
    cast_f32_bf16<<<2048, 256, 0, stream>>>(Wih,  wih_b,  G4_ * H_);
    cast_f32_bf16<<<2048, 256, 0, stream>>>(Whh,  whh_b,  G4_ * H_);
    cast_f32_bf16<<<72,   256, 0, stream>>>(Wdec, wdec_b, A_ * H_);
    add_bias2<<<16, 256, 0, stream>>>(bih, bhh, bias2, G4_);
    init_scan<<<2048, 256, 0, stream>>>(h_buf0, c_f32, flags);

    if (big){
        u16* h_buf1  = (u16*)alloc(hbuf_b);
        u16* enc_all = (u16*)alloc(enc_all_b);
        u16* xg_buf0 = (u16*)alloc(xg_b);
        u16* xg_buf1 = (u16*)alloc(xg_b);
        u16* xg_buf[2] = { xg_buf0, xg_buf1 };
        u16* h_buf[2]  = { h_buf0, h_buf1 };

        // enc for ALL chunks up front (depends only on inputs)
        dim3 ge(H_ / 128, MM_ / 128);
        gemm_bt<true, true><<<ge, 256, 0, stream>>>(
            obs, wenc_b, benc, enc_all, MM_, H_, OBS_);

        // xg for chunk 0
        dim3 gx(G4_ / 128, CM_ / 128);
        gemm_bt<false, false><<<gx, 256, 0, stream>>>(
            enc_all, wih_b, bias2, xg_buf[0], CM_, G4_, H_);

        for (int c = 0; c < NCH_; c++){
            const int t0 = c * CH_;
            const int nt = (c + 1 < NCH_) ? 1024 : 0;
            const u16*  dlat = (c > 0) ? h_buf[(c - 1) & 1] + (size_t)B_ * H_ : nullptr;
            const float* dmk = (c > 0) ? mask + (size_t)(c - 1) * CH_ * B_ : mask;
            float*      dout = (c > 0) ? out + (size_t)(c - 1) * CM_ * A_ : out;

            fused_scan_gemm<<<256 + NG_, 256, 0, stream>>>(
                xg_buf[c & 1], whh_b, h_buf[c & 1], h_buf[(c + 1) & 1],
                c_f32, h_f32, mask + (size_t)t0 * B_, flags, t0,
                enc_all + (size_t)(c + 1 < NCH_ ? c + 1 : 0) * CM_ * H_,
                wih_b, bias2, xg_buf[(c + 1) & 1], nt,
                wdec_b, bdec, dlat, dmk, dout);
        }

        // final chunk's decode (no following fused dispatch to absorb it)
        decode_kernel<<<256, 256, 0, stream>>>(
            h_buf[(NCH_ - 1) & 1] + (size_t)B_ * H_, wdec_b, bdec,
            mask + (size_t)(NCH_ - 1) * CH_ * B_,
            out + (size_t)(NCH_ - 1) * CM_ * A_, CM_);
    } else {
        // fallback: chunked serial schedule (R1 structure + setprio)
        u16* enc_ch = (u16*)alloc((size_t)CM_ * H_ * 2);
        u16* xg_ch  = (u16*)alloc(xg_b);

        for (int c = 0; c < NCH_; c++){
            const int t0 = c * CH_;

            dim3 g1(H_ / 128, CM_ / 128);
            gemm_bt<true, true><<<g1, 256, 0, stream>>>(
                obs + (size_t)t0 * B_ * OBS_, wenc_b, benc, enc_ch, CM_, H_, OBS_);

            dim3 g2(G4_ / 128, CM_ / 128);
            gemm_bt<false, false><<<g2, 256, 0, stream>>>(
                enc_ch, wih_b, bias2, xg_ch, CM_, G4_, H_);

            fused_scan_gemm<<<256, 256, 0, stream>>>(
                xg_ch, whh_b, h_buf0, h_buf0, c_f32, h_f32,
                mask + (size_t)t0 * B_, flags, t0,
                (const u16*)nullptr, wih_b, bias2, (u16*)nullptr, 0,
                wdec_b, bdec, (const u16*)nullptr, mask, out);

            decode_kernel<<<256, 256, 0, stream>>>(
                h_buf0 + (size_t)B_ * H_, wdec_b, bdec, mask + (size_t)t0 * B_,
                out + (size_t)t0 * B_ * A_, CM_);
        }
    }

    copy_hc<<<256, 256, 0, stream>>>(h_f32, c_f32, out);
}

// Round 4
// 2574.959 us; speedup vs baseline: 1.1095x; 1.1095x over previous
//
#include <hip/hip_runtime.h>
#include <hip/hip_bf16.h>

#define T_ 512
#define B_ 64
#define OBS_ 512
#define H_ 1024
#define A_ 18
#define MM_ (T_*B_)   // 32768
#define G4_ (4*H_)    // 4096
#define CH_ 64        // time steps per chunk
#define NCH_ (T_/CH_) // 8 chunks
#define CM_ (CH_*B_)  // 4096 rows per chunk

typedef unsigned short u16;
typedef unsigned long long u64;
typedef __attribute__((ext_vector_type(8))) short s8v;
typedef __attribute__((ext_vector_type(4))) float f4v;

__device__ __forceinline__ float b2f(u16 u){
    unsigned x = ((unsigned)u) << 16;
    return __builtin_bit_cast(float, x);
}
__device__ __forceinline__ u16 f2b(float f){
    unsigned x = __builtin_bit_cast(unsigned, f);
    return (u16)((x + 0x7fffu + ((x >> 16) & 1u)) >> 16);  // RNE
}

// fast sigmoid/tanh: v_exp + v_rcp (error << bf16 quantum; correct at +-inf)
__device__ __forceinline__ float fsig(float x){
    return __builtin_amdgcn_rcpf(1.f + __expf(-x));
}
__device__ __forceinline__ float ftanh(float x){
    return 1.f - 2.f * __builtin_amdgcn_rcpf(__expf(2.f * x) + 1.f);
}

// ---------------- prologue: all casts + bias + zeroing in ONE dispatch ----------------

__global__ void prep_all(const float* __restrict__ Wenc, const float* __restrict__ Wih,
                         const float* __restrict__ Whh, const float* __restrict__ Wdec,
                         const float* __restrict__ bih, const float* __restrict__ bhh,
                         u16* __restrict__ wenc_b, u16* __restrict__ wih_b,
                         u16* __restrict__ whh_b, u16* __restrict__ wdec_b,
                         float* __restrict__ bias2, u16* __restrict__ h_hist,
                         float* __restrict__ c_f32, unsigned* __restrict__ flags)
{
    int i = blockIdx.x * blockDim.x + threadIdx.x;
    int stride = gridDim.x * blockDim.x;
    for (int k = i; k < G4_ * H_; k += stride){
        wih_b[k] = f2b(Wih[k]);
        whh_b[k] = f2b(Whh[k]);
    }
    for (int k = i; k < H_ * OBS_; k += stride) wenc_b[k] = f2b(Wenc[k]);
    for (int k = i; k < A_ * H_; k += stride) wdec_b[k] = f2b(Wdec[k]);
    for (int k = i; k < G4_; k += stride) bias2[k] = bih[k] + bhh[k];
    unsigned* h0 = (unsigned*)h_hist;
    for (int k = i; k < B_ * H_ / 2; k += stride) h0[k] = 0u;
    for (int k = i; k < B_ * H_; k += stride) c_f32[k] = 0.f;
    for (int k = i; k < 1024; k += stride) flags[k] = 0u;
}

__global__ void copy_hc(const float* __restrict__ h, const float* __restrict__ c,
                        float* __restrict__ out){
    int i = blockIdx.x * blockDim.x + threadIdx.x;  // 65536 threads
    out[(size_t)MM_*A_ + i] = h[i];
    out[(size_t)MM_*A_ + B_*H_ + i] = c[i];
}

// ---------------- bf16 MFMA GEMM: C = act(A @ W^T + bias), W is (N,K) ----------------

#define LDSS 72  // 64 + 8 pad

template<bool A_FP32, bool RELU>
__global__ __launch_bounds__(256) void gemm_bt(
    const void* __restrict__ Aptr, const u16* __restrict__ W,
    const float* __restrict__ bias, u16* __restrict__ C,
    int M, int N, int K)
{
    __shared__ __align__(16) u16 As[128 * LDSS];
    __shared__ __align__(16) u16 Bs[128 * LDSS];

    const int tid  = threadIdx.x;
    const int lane = tid & 63;
    const int wid  = tid >> 6;
    const int wm   = wid & 1, wn = wid >> 1;
    const int m0   = blockIdx.y * 128, n0 = blockIdx.x * 128;
    const int quad = lane >> 4, l16 = lane & 15;

    f4v acc[4][4];
    #pragma unroll
    for (int i = 0; i < 4; i++)
        #pragma unroll
        for (int j = 0; j < 4; j++) acc[i][j] = (f4v){0.f,0.f,0.f,0.f};

    for (int k0 = 0; k0 < K; k0 += 64){
        __syncthreads();
        if (A_FP32){
            const float* A = (const float*)Aptr;
            #pragma unroll
            for (int pss = 0; pss < 8; pss++){
                int idx = pss * 256 + tid;
                int row = idx >> 4, ch = idx & 15;
                float4 v = *(const float4*)(A + (size_t)(m0 + row) * K + k0 + ch * 4);
                u16* d = &As[row * LDSS + ch * 4];
                d[0] = f2b(v.x); d[1] = f2b(v.y); d[2] = f2b(v.z); d[3] = f2b(v.w);
            }
        } else {
            const u16* A = (const u16*)Aptr;
            #pragma unroll
            for (int pss = 0; pss < 4; pss++){
                int idx = pss * 256 + tid;
                int row = idx >> 3, ch = idx & 7;
                *(uint4*)&As[row * LDSS + ch * 8] =
                    *(const uint4*)(A + (size_t)(m0 + row) * K + k0 + ch * 8);
            }
        }
        #pragma unroll
        for (int pss = 0; pss < 4; pss++){
            int idx = pss * 256 + tid;
            int row = idx >> 3, ch = idx & 7;
            *(uint4*)&Bs[row * LDSS + ch * 8] =
                *(const uint4*)(W + (size_t)(n0 + row) * K + k0 + ch * 8);
        }
        __syncthreads();

        #pragma unroll
        for (int kk = 0; kk < 64; kk += 32){
            s8v af[4], bf[4];
            #pragma unroll
            for (int mt = 0; mt < 4; mt++)
                af[mt] = *(const s8v*)&As[(wm*64 + mt*16 + l16) * LDSS + kk + quad*8];
            #pragma unroll
            for (int nt = 0; nt < 4; nt++)
                bf[nt] = *(const s8v*)&Bs[(wn*64 + nt*16 + l16) * LDSS + kk + quad*8];
            #pragma unroll
            for (int mt = 0; mt < 4; mt++)
                #pragma unroll
                for (int nt = 0; nt < 4; nt++)
                    acc[mt][nt] = __builtin_amdgcn_mfma_f32_16x16x32_bf16(
                        af[mt], bf[nt], acc[mt][nt], 0, 0, 0);
        }
    }

    #pragma unroll
    for (int mt = 0; mt < 4; mt++){
        #pragma unroll
        for (int nt = 0; nt < 4; nt++){
            #pragma unroll
            for (int r = 0; r < 4; r++){
                int m = m0 + wm*64 + mt*16 + quad*4 + r;
                int n = n0 + wn*64 + nt*16 + l16;
                float v = acc[mt][nt][r] + bias[n];
                if (RELU) v = fmaxf(v, 0.f);
                C[(size_t)m * N + n] = f2b(v);
            }
        }
    }
}

// ---------------- persistent LSTM scan, PER-WAVE flag rendezvous ----------------
// 256 blocks = 4 batch-groups (16 rows) x 64 N-slices (16 units). Proven R1
// protocol, refined: flags are now per (group, slice, WAVE) -- [4][64][4] u32.
// Producer wave w (cell rows 4w..4w+3, all 16 units of its slice) publishes
// its own piece right after ITS OWN vmcnt(0): no intra-block syncthreads on
// the publish path (the red[]-guard barrier moves AFTER the flag store and
// overlaps with the next poll). Consumer wave w needs h[16 rows][koff..koff+255]
// = slices 16w..16w+15, ALL waves of each: flag indices g*256 + 64w + lane --
// one contiguous dword/lane, 2 lines, 64 pollers/line (same as R1).
// Coverage identical: union of the 4 per-wave flags of a block == old block flag.
// Cell math uses v_rcp/v_exp forms (libm tanhf x2 + 3 divisions were on the
// serial chain between h-ready and publish).

__global__ __launch_bounds__(256, 1) void lstm_scan(
    const u16* __restrict__ xg,      // [CH_][64][4096] chunk-local
    const u16* __restrict__ Whh,     // [4096][1024]
    u16* __restrict__ h_hist,        // [CH_+1][64][1024]; [0] = incoming h
    float* __restrict__ c_glob,      // [64][1024] fp32, persists across chunks
    float* __restrict__ h_f32,       // final-h staging (t == T-1 only)
    const float* __restrict__ mask,  // chunk-local
    unsigned* __restrict__ flags,    // [4][64][4] per-wave monotonic step flags
    int t0)
{
    __shared__ float red[4][4][16][17];  // [wave][gate][batch][unit(+pad)] ~17.4 KB

    const int tid  = threadIdx.x;
    const int lane = tid & 63;
    const int w    = tid >> 6;
    const int quad = lane >> 4, l16 = lane & 15;
    const int bid  = blockIdx.x;
    const int g = bid & 3, s = bid >> 2;
    const int rb0 = g * 16, j0 = s * 16;

    // Whh B-fragments: B[n=lane&15][k=quad*8+j] [m89]
    const int koff = w * 256;
    s8v bf[4][8];
    #pragma unroll
    for (int gate = 0; gate < 4; gate++)
        #pragma unroll
        for (int ks = 0; ks < 8; ks++)
            bf[gate][ks] = *(const s8v*)(
                Whh + (size_t)(gate * H_ + j0 + l16) * H_ + koff + ks * 32 + quad * 8);

    const int cb = tid >> 4, cu = tid & 15;
    const size_t cidx = (size_t)(rb0 + cb) * H_ + j0 + cu;
    float c_reg = c_glob[cidx];

    const size_t hoff = (size_t)(rb0 + l16) * H_ + koff + quad * 8;  // u16 elems

    // producer: flags[g][s][w]; consumer wave w: flags[g][16w + lane>>2][lane&3]
    unsigned* myflag = flags + (g << 8) + (s << 2) + w;
    const unsigned* pollp = flags + (g << 8) + (w << 6) + lane;

    // prefetch xg + mask for st = 0
    const u16* xg0 = xg + (size_t)(rb0 + cb) * G4_ + j0 + cu;
    u16 nxi = xg0[0], nxf = xg0[H_], nxv = xg0[2 * H_], nxo = xg0[3 * H_];
    float nm = mask[rb0 + cb];

    for (int st = 0; st < CH_; st++){
        const float xi = b2f(nxi), xf = b2f(nxf), xv = b2f(nxv), xo = b2f(nxo);
        const float m = nm;

        // ---- per-wave flag poll: 16 producer blocks x 4 waves of this K-quarter
        const unsigned tgt = (unsigned)(t0 + st);
        int tries = 0;
        for (;;){
            unsigned f = __hip_atomic_load(pollp, __ATOMIC_RELAXED, __HIP_MEMORY_SCOPE_AGENT);
            if (__all((int)(f >= tgt))) break;
            if (++tries > (1 << 20)) break;  // backstop: fail visibly, never hang
            if (tries >= 8) __builtin_amdgcn_s_sleep(1);  // thin the poll storm
        }

        // ---- h loads (fresh: first touch after gate) + MFMA
        const u16* hs = h_hist + (size_t)st * B_ * H_ + hoff;
        f4v acc[4];
        #pragma unroll
        for (int gate = 0; gate < 4; gate++) acc[gate] = (f4v){0.f,0.f,0.f,0.f};
        #pragma unroll
        for (int ks = 0; ks < 8; ks++){
            s8v af = *(const s8v*)(hs + ks * 32);
            #pragma unroll
            for (int gate = 0; gate < 4; gate++)
                acc[gate] = __builtin_amdgcn_mfma_f32_16x16x32_bf16(af, bf[gate][ks], acc[gate], 0, 0, 0);
        }
        #pragma unroll
        for (int gate = 0; gate < 4; gate++)
            #pragma unroll
            for (int r = 0; r < 4; r++)
                red[w][gate][quad * 4 + r][l16] = acc[gate][r];
        __syncthreads();  // SYNC1: red[] complete before cell reads

        // ---- cell phase (fast transcendental forms)
        float gi = xi, gf = xf, gg = xv, go = xo;
        #pragma unroll
        for (int ww = 0; ww < 4; ww++){
            gi += red[ww][0][cb][cu];
            gf += red[ww][1][cb][cu];
            gg += red[ww][2][cb][cu];
            go += red[ww][3][cb][cu];
        }

        float is = fsig(gi);
        float fs = fsig(gf);
        float os = fsig(go);
        float gt = ftanh(gg);

        float cn = fs * c_reg + is * gt;
        float hn = os * ftanh(cn);
        hn *= m; cn *= m;
        c_reg = cn;
        if (t0 + st == T_ - 1) h_f32[cidx] = hn;

        // ---- publish h(st+1): packed u32 sc1 store to LLC (this wave: rows 4w..4w+3)
        unsigned hb = (unsigned)f2b(hn);
        unsigned partner = (unsigned)__shfl_xor((int)hb, 1, 64);
        if ((cu & 1) == 0){
            unsigned packed = hb | (partner << 16);
            unsigned* dst = (unsigned*)(h_hist + (size_t)(st + 1) * B_ * H_ + cidx);
            __hip_atomic_store(dst, packed, __ATOMIC_RELAXED, __HIP_MEMORY_SCOPE_AGENT);
            if (st == CH_ - 1){  // seed next chunk's h_hist[0]
                unsigned* dst0 = (unsigned*)(h_hist + cidx);
                __hip_atomic_store(dst0, packed, __ATOMIC_RELAXED, __HIP_MEMORY_SCOPE_AGENT);
            }
        }
        asm volatile("s_waitcnt vmcnt(0)" ::: "memory");  // this wave's h stores acked

        // ---- release: THIS WAVE's flag (covers exactly this wave's stores)
        if (lane == 0)
            __hip_atomic_store(myflag, (unsigned)(t0 + st + 1),
                               __ATOMIC_RELAXED, __HIP_MEMORY_SCOPE_AGENT);

        // ---- prefetch next step's xg/mask (outside vmcnt window)
        if (st + 1 < CH_){
            const u16* xgn = xg + (size_t)(st + 1) * B_ * G4_ + (size_t)(rb0 + cb) * G4_ + j0 + cu;
            nxi = xgn[0]; nxf = xgn[H_]; nxv = xgn[2 * H_]; nxo = xgn[3 * H_];
            nm = mask[(size_t)(st + 1) * B_ + rb0 + cb];
        }

        __syncthreads();  // SYNC2 (moved off publish path): guards red[] reuse
    }

    c_glob[cidx] = c_reg;
}

// ---------------- decode ----------------

__global__ __launch_bounds__(256) void decode_kernel(
    const u16* __restrict__ latent, const u16* __restrict__ Wdec,
    const float* __restrict__ bdec, const float* __restrict__ mask,
    float* __restrict__ values, int rows)
{
    __shared__ __align__(16) u16 wl[A_ * H_];
    const int tid = threadIdx.x;
    for (int i = tid; i < A_ * H_ / 8; i += 256)
        ((uint4*)wl)[i] = ((const uint4*)Wdec)[i];
    __syncthreads();

    const int lane = tid & 63;
    int wid = blockIdx.x * 4 + (tid >> 6);
    const int nwaves = gridDim.x * 4;

    for (int row = wid; row < rows; row += nwaves){
        float lat[16];
        #pragma unroll
        for (int i = 0; i < 16; i++)
            lat[i] = b2f(latent[(size_t)row * H_ + i*64 + lane]);
        float acc[A_];
        #pragma unroll
        for (int a = 0; a < A_; a++) acc[a] = 0.f;
        #pragma unroll
        for (int i = 0; i < 16; i++){
            #pragma unroll
            for (int a = 0; a < A_; a++)
                acc[a] += lat[i] * b2f(wl[a * H_ + i*64 + lane]);
        }
        float m = mask[row];
        #pragma unroll
        for (int a = 0; a < A_; a++){
            float v = acc[a];
            #pragma unroll
            for (int s = 32; s > 0; s >>= 1) v += __shfl_down(v, s, 64);
            if (lane == 0) values[(size_t)row * A_ + a] = (v + bdec[a]) * m;
        }
    }
}

// ---------------- launcher ----------------

extern "C" void kernel_launch(void* const* d_in, const int* in_sizes, int n_in,
                              void* d_out, int out_size, void* d_ws, size_t ws_size,
                              hipStream_t stream)
{
    const float* obs  = (const float*)d_in[0];
    const float* mask = (const float*)d_in[1];
    const float* Wenc = (const float*)d_in[2];
    const float* benc = (const float*)d_in[3];
    const float* Wih  = (const float*)d_in[4];
    const float* bih  = (const float*)d_in[5];
    const float* Whh  = (const float*)d_in[6];
    const float* bhh  = (const float*)d_in[7];
    const float* Wdec = (const float*)d_in[8];
    const float* bdec = (const float*)d_in[9];
    float* out = (float*)d_out;

    char* p = (char*)d_ws;
    size_t o = 0;
    auto alloc = [&](size_t bytes){ void* r = p + o; o += (bytes + 255) & ~(size_t)255; return r; };
    u16*      wenc_b  = (u16*)     alloc((size_t)H_ * OBS_ * 2);
    u16*      wih_b   = (u16*)     alloc((size_t)G4_ * H_ * 2);
    u16*      whh_b   = (u16*)     alloc((size_t)G4_ * H_ * 2);
    u16*      wdec_b  = (u16*)     alloc((size_t)A_ * H_ * 2);
    float*    bias2   = (float*)   alloc((size_t)G4_ * 4);
    u16*      h_hist  = (u16*)     alloc((size_t)(CH_ + 1) * B_ * H_ * 2);  // 8.3 MB
    float*    h_f32   = (float*)   alloc((size_t)B_ * H_ * 4);
    float*    c_f32   = (float*)   alloc((size_t)B_ * H_ * 4);
    unsigned* flags   = (unsigned*)alloc(1024 * 4);  // [4][64][4] u32
    u16*      xg_ch   = (u16*)     alloc((size_t)CM_ * G4_ * 2);  // 33.5 MB

    const size_t enc_all_b = (size_t)MM_ * H_ * 2;   // 67.1 MB
    const bool big = ws_size >= o + enc_all_b + 4096;
    (void)in_sizes; (void)n_in; (void)out_size;

    prep_all<<<2048, 256, 0, stream>>>(Wenc, Wih, Whh, Wdec, bih, bhh,
                                       wenc_b, wih_b, whh_b, wdec_b,
                                       bias2, h_hist, c_f32, flags);

    if (big){
        u16* enc_all = (u16*)alloc(enc_all_b);

        // enc for ALL chunks in one dispatch (depends only on inputs)
        dim3 ge(H_ / 128, MM_ / 128);
        gemm_bt<true, true><<<ge, 256, 0, stream>>>(
            obs, wenc_b, benc, enc_all, MM_, H_, OBS_);

        for (int c = 0; c < NCH_; c++){
            const int t0 = c * CH_;

            dim3 gx(G4_ / 128, CM_ / 128);
            gemm_bt<false, false><<<gx, 256, 0, stream>>>(
                enc_all + (size_t)c * CM_ * H_, wih_b, bias2, xg_ch, CM_, G4_, H_);

            lstm_scan<<<256, 256, 0, stream>>>(
                xg_ch, whh_b, h_hist, c_f32, h_f32,
                mask + (size_t)t0 * B_, flags, t0);

            decode_kernel<<<256, 256, 0, stream>>>(
                h_hist + (size_t)B_ * H_, wdec_b, bdec, mask + (size_t)t0 * B_,
                out + (size_t)t0 * B_ * A_, CM_);
        }
    } else {
        u16* enc_ch = (u16*)alloc((size_t)CM_ * H_ * 2);

        for (int c = 0; c < NCH_; c++){
            const int t0 = c * CH_;

            dim3 g1(H_ / 128, CM_ / 128);
            gemm_bt<true, true><<<g1, 256, 0, stream>>>(
                obs + (size_t)t0 * B_ * OBS_, wenc_b, benc, enc_ch, CM_, H_, OBS_);

            dim3 g2(G4_ / 128, CM_ / 128);
            gemm_bt<false, false><<<g2, 256, 0, stream>>>(
                enc_ch, wih_b, bias2, xg_ch, CM_, G4_, H_);

            lstm_scan<<<256, 256, 0, stream>>>(
                xg_ch, whh_b, h_hist, c_f32, h_f32,
                mask + (size_t)t0 * B_, flags, t0);

            decode_kernel<<<256, 256, 0, stream>>>(
                h_hist + (size_t)B_ * H_, wdec_b, bdec, mask + (size_t)t0 * B_,
                out + (size_t)t0 * B_ * A_, CM_);
        }
    }

    copy_hc<<<256, 256, 0, stream>>>(h_f32, c_f32, out);
}